// Round 18
// baseline (87.358 us; speedup 1.0000x reference)
//
#include <hip/hip_runtime.h>
#include <hip/hip_bf16.h>

typedef __attribute__((ext_vector_type(4))) float f32x4;
typedef __attribute__((ext_vector_type(8))) short bf16x8;

#define MFMA16(A, B, C) __builtin_amdgcn_mfma_f32_16x16x32_bf16(A, B, C, 0, 0, 0)

// 2*log2(e): tanh(x) = 1 - 2/(1 + 2^(C2*x))
#define C2 2.8853900817779268f
// C2 / sqrt(128), folded into Wq/bq so MFMA output is already exp2-scaled
#define QS (2.8853900817779268f / 11.313708498984761f)

__device__ __forceinline__ unsigned cvtpk_bf16(float lo, float hi) {
    unsigned r;
    asm("v_cvt_pk_bf16_f32 %0, %1, %2" : "=v"(r) : "v"(lo), "v"(hi));
    return r;
}

__device__ __forceinline__ bf16x8 pack8(float4 a, float4 b) {
    union { unsigned u[4]; bf16x8 v; } u;
    u.u[0] = cvtpk_bf16(a.x, a.y);
    u.u[1] = cvtpk_bf16(a.z, a.w);
    u.u[2] = cvtpk_bf16(b.x, b.y);
    u.u[3] = cvtpk_bf16(b.z, b.w);
    return u.v;
}

// async global->LDS, 16B per lane; LDS dest = wave-uniform base + lane*16
__device__ __forceinline__ void gload_lds16(const void* g, void* l) {
    __builtin_amdgcn_global_load_lds(
        (const __attribute__((address_space(1))) unsigned int*)g,
        (__attribute__((address_space(3))) unsigned int*)l, 16, 0, 0);
}

// ---------------------------------------------------------------------------
// Kernel 1: transpose + convert weights to bf16, fold scales, stash biases.
// ---------------------------------------------------------------------------
__global__ void prep_weights(const float* __restrict__ Wq, const float* __restrict__ bq,
                             const float* __restrict__ Wk, const float* __restrict__ bk,
                             const float* __restrict__ Wv, const float* __restrict__ bv,
                             __hip_bfloat16* __restrict__ Wqt, __hip_bfloat16* __restrict__ Wkt,
                             __hip_bfloat16* __restrict__ Wvt, float* __restrict__ bias) {
    int i = blockIdx.x * 256 + threadIdx.x;  // 64 blocks * 256 = 16384 exactly
    int k = i >> 7, o = i & 127;
    Wqt[o * 128 + k] = __float2bfloat16(Wq[i] * QS);
    Wkt[o * 128 + k] = __float2bfloat16(Wk[i]);
    Wvt[o * 128 + k] = __float2bfloat16(Wv[i] * 0.25f);  // head-mean folded into V
    if (i < 128) {
        bias[i]       = bq[i] * QS;
        bias[128 + i] = bk[i];
        bias[256 + i] = bv[i] * 0.25f;
    }
}

// ---------------------------------------------------------------------------
// Kernel 2: Q/K/V projections via 16x16x32 bf16 MFMA.
//   Qo, Ko: row-major [B*N][128] bf16 (Q pre-scaled by C2/sqrt(128))
//   Vt:     transposed [B][128][N] bf16 (pre-scaled by 0.25)
// ---------------------------------------------------------------------------
__global__ __launch_bounds__(256) void proj_qkv(
        const float* __restrict__ x, const float* __restrict__ cond,
        const __hip_bfloat16* __restrict__ Wqt, const __hip_bfloat16* __restrict__ Wkt,
        const __hip_bfloat16* __restrict__ Wvt, const float* __restrict__ bias,
        __hip_bfloat16* __restrict__ Qo, __hip_bfloat16* __restrict__ Ko,
        __hip_bfloat16* __restrict__ Vt) {
    const int lane = threadIdx.x & 63, wv = threadIdx.x >> 6;
    const int l15 = lane & 15, g = lane >> 4;
    const int row0 = blockIdx.x * 64 + wv * 16;   // 256 blocks x 64 rows

    f32x4 qa[8], ka[8], va[8];
#pragma unroll
    for (int ot = 0; ot < 8; ++ot) {
        float b0 = bias[16 * ot + l15];
        float b1 = bias[128 + 16 * ot + l15];
        float b2 = bias[256 + 16 * ot + l15];
        qa[ot] = (f32x4){b0, b0, b0, b0};
        ka[ot] = (f32x4){b1, b1, b1, b1};
        va[ot] = (f32x4){b2, b2, b2, b2};
    }

    const float* xp = x    + (size_t)(row0 + l15) * 128 + 8 * g;
    const float* cp = cond + (size_t)(row0 + l15) * 128 + 8 * g;
#pragma unroll
    for (int kk = 0; kk < 4; ++kk) {
        float4 x0 = *(const float4*)(xp + 32 * kk);
        float4 x1 = *(const float4*)(xp + 32 * kk + 4);
        float4 c0 = *(const float4*)(cp + 32 * kk);
        float4 c1 = *(const float4*)(cp + 32 * kk + 4);
        bf16x8 xa = pack8(x0, x1);
        bf16x8 ca = pack8(c0, c1);
#pragma unroll
        for (int ot = 0; ot < 8; ++ot) {
            const int wo = (16 * ot + l15) * 128 + 32 * kk + 8 * g;
            qa[ot] = MFMA16(xa, *(const bf16x8*)(Wqt + wo), qa[ot]);
            ka[ot] = MFMA16(ca, *(const bf16x8*)(Wkt + wo), ka[ot]);
            va[ot] = MFMA16(ca, *(const bf16x8*)(Wvt + wo), va[ot]);
        }
    }

    // Q, K row-major stores (C/D layout: row = 4g+r, col = 16ot+l15)
#pragma unroll
    for (int ot = 0; ot < 8; ++ot)
#pragma unroll
        for (int r = 0; r < 4; ++r) {
            size_t idx = (size_t)(row0 + 4 * g + r) * 128 + 16 * ot + l15;
            Qo[idx] = __float2bfloat16(qa[ot][r]);
            Ko[idx] = __float2bfloat16(ka[ot][r]);
        }
    // V transposed store: lane holds 4 consecutive n for fixed d -> dwordx2
    const int bb = row0 >> 11, nn = (row0 & 2047) + 4 * g;
#pragma unroll
    for (int ot = 0; ot < 8; ++ot) {
        uint2 pr;
        pr.x = cvtpk_bf16(va[ot][0], va[ot][1]);
        pr.y = cvtpk_bf16(va[ot][2], va[ot][3]);
        *(uint2*)((unsigned short*)Vt + ((size_t)bb * 128 + 16 * ot + l15) * 2048 + nn) = pr;
    }
}

// ---------------------------------------------------------------------------
// Kernel 3: fused tanh-attention, LDS-staged, fragment-reuse (R18).
// R12 structure (sync/staging/barriers identical) with re-partitioned wave
// work to cut LDS-port traffic (the last unfalsified bottleneck: per-CU
// read traffic ~4.6 MB at 128 B/cyc += conflicts ~= wall time; invisible in
// the PMC set):
//   QK: wave (qp=w&1, mt=w>>1) covers 32q x 16m: K-frags (4 b128) loaded
//       ONCE into regs, reused across 2 Q-fragment sets -> 4 reads / 8 MFMA
//       (R12: 8 reads / 8 MFMA).
//   PV: wave (qp, dp=w>>1) covers 32q x 32d: vf reused across 2 q-tiles,
//       af across 2 d-tiles -> 8 reads / 8 MFMA (R12: 10).
// Per-wave per-chunk LDS reads 18 KB -> 12 KB (-33%). MFMA count, VALU
// work, barriers, staging, XCD pinning, atomics all unchanged.
// ---------------------------------------------------------------------------
__global__ __launch_bounds__(512, 4) void attn_main(
        const __hip_bfloat16* __restrict__ Q, const __hip_bfloat16* __restrict__ K,
        const __hip_bfloat16* __restrict__ Vt, const float* __restrict__ mask,
        float* __restrict__ out) {
    __shared__ __align__(16) char Kl[2][16384];   // [64 m][256B] per buf
    __shared__ __align__(16) char Vl[2][16384];   // [128 d][128B] per buf
    __shared__ __align__(16) char Al[64 * 144];   // [64 q][72 bf16]

    const int lane = threadIdx.x & 63, w = threadIdx.x >> 6;
    const int l15 = lane & 15, g = lane >> 4;
    const int qp = w & 1;          // 32-q half (QK and PV)
    const int mt = w >> 1;         // QK: 16-m slice (0..3)
    const int dp = w >> 1;         // PV: 32-d slice (0..3)
    // XCD-pinned decomposition: batch = blockIdx & 7 (== XCD under round-robin)
    const int b  = blockIdx.x & 7;
    const int r2 = blockIdx.x >> 3;
    const int qt = r2 & 31;
    const int mh = r2 >> 5;
    const int n0 = qt * 64;
    const int mh0 = mh * 1024;

    const __hip_bfloat16* Qb = Q + ((size_t)b * 2048 + n0 + qp * 32) * 128;
    const char* Kg = (const char*)(K + (size_t)b * 2048 * 128);
    const char* Vg = (const char*)(Vt + (size_t)b * 128 * 2048);
    // mask rows for the wave's two q-tiles, m = mh0 + mt*16 + 4g
    const float* mrow0 = mask + ((size_t)b * 2048 + n0 + qp * 32 + l15) * 2048
                         + mh0 + mt * 16 + 4 * g;
    const float* mrow1 = mrow0 + (size_t)16 * 2048;

    bf16x8 qf[2][4];               // 2 q-tiles x 4 heads
#pragma unroll
    for (int p = 0; p < 2; ++p)
#pragma unroll
        for (int h = 0; h < 4; ++h)
            qf[p][h] = *(const bf16x8*)(Qb + (p * 16 + l15) * 128 + 32 * h + 8 * g);

    f32x4 oacc[2][2];              // [q-tile][d-tile], 32q x 32d per wave
#pragma unroll
    for (int i = 0; i < 2; ++i)
#pragma unroll
        for (int j = 0; j < 2; ++j) oacc[i][j] = (f32x4){0.f, 0.f, 0.f, 0.f};
    const f32x4 zero = (f32x4){0.f, 0.f, 0.f, 0.f};

    // ---- staging: 2 K-instr + 2 V-instr per wave (1 KB each, linear LDS) --
    auto STAGE = [&](int m0g, int bi) {
#pragma unroll
        for (int i = 0; i < 2; ++i) {
            const int t = w * 2 + i;
            const int o = t * 1024 + lane * 16;
            const int kr = o >> 8, kc = o & 255;
            gload_lds16(Kg + (size_t)(m0g + kr) * 256 + (kc ^ ((kr & 7) << 4)),
                        &Kl[bi][t * 1024]);
            const int vr = o >> 7, vc = o & 127;
            gload_lds16(Vg + (size_t)vr * 4096 + (size_t)m0g * 2 + (vc ^ ((vr & 7) << 4)),
                        &Vl[bi][t * 1024]);
        }
    };

    // prologue: stage chunk 0, prefetch mask chunk 0
    STAGE(mh0, 0);
    f32x4 mkc0 = *(const f32x4*)(mrow0);
    f32x4 mkc1 = *(const f32x4*)(mrow1);
    asm volatile("s_waitcnt vmcnt(0)" ::: "memory");
    __builtin_amdgcn_s_barrier();

#pragma unroll 2
    for (int c = 0; c < 16; ++c) {
        const int bi = c & 1;
        const int m0g = mh0 + c * 64;
        // issue next chunk's stage + mask prefetch (stay in flight all chunk)
        if (c < 15) STAGE(m0g + 64, bi ^ 1);
        f32x4 mkn0, mkn1;
        if (c < 15) {
            mkn0 = *(const f32x4*)(mrow0 + (c + 1) * 64);
            mkn1 = *(const f32x4*)(mrow1 + (c + 1) * 64);
        }

        // ---- QK + tanh + A-write: wave's 32q x 16m; K-frags read once ----
        {
            const int mr = mt * 16 + l15;            // K row within chunk
            const char* kb = &Kl[bi][mr * 256];
            const int sw = (mr & 7) << 4;
            bf16x8 kfr[4];
#pragma unroll
            for (int h = 0; h < 4; ++h)
                kfr[h] = *(const bf16x8*)(kb + ((64 * h + 16 * g) ^ sw));
#pragma unroll
            for (int p = 0; p < 2; ++p) {
                f32x4 s0 = MFMA16(kfr[0], qf[p][0], zero);
                f32x4 s1 = MFMA16(kfr[1], qf[p][1], zero);
                f32x4 s2 = MFMA16(kfr[2], qf[p][2], zero);
                f32x4 s3 = MFMA16(kfr[3], qf[p][3], zero);
                const f32x4 mk = p ? mkc1 : mkc0;
                float acd[4];
#pragma unroll
                for (int r = 0; r < 4; ++r) {
                    // sum_h 1/(1+e_h) = N/D with a single rcp
                    float t0 = 1.f + __builtin_amdgcn_exp2f(fmaf(mk[r], C2, s0[r]));
                    float t1 = 1.f + __builtin_amdgcn_exp2f(fmaf(mk[r], C2, s1[r]));
                    float t2 = 1.f + __builtin_amdgcn_exp2f(fmaf(mk[r], C2, s2[r]));
                    float t3 = 1.f + __builtin_amdgcn_exp2f(fmaf(mk[r], C2, s3[r]));
                    float pp = t0 * t1, qq = t2 * t3;
                    float nn = fmaf(t0 + t1, qq, (t2 + t3) * pp);
                    float rs = nn * __builtin_amdgcn_rcpf(pp * qq);
                    acd[r] = fmaf(-2.f, rs, 4.f);
                }
                uint2 pk;
                pk.x = cvtpk_bf16(acd[0], acd[1]);
                pk.y = cvtpk_bf16(acd[2], acd[3]);
                // A[q = qp*32 + p*16 + l15][m = mt*16 + 4g + 0..3]
                *(uint2*)(Al + (qp * 32 + p * 16 + l15) * 144 + (mt * 16 + 4 * g) * 2) = pk;
            }
        }

        // A visible block-wide; do NOT drain vmcnt (stage stays in flight)
        asm volatile("s_waitcnt lgkmcnt(0)" ::: "memory");
        __builtin_amdgcn_s_barrier();

        // ---- PV: wave's 32q x 32d over this chunk's 64 m; frag reuse ----
#pragma unroll
        for (int ks = 0; ks < 2; ++ks) {
            bf16x8 af0 = *(const bf16x8*)(Al + (qp * 32 + l15) * 144 + (ks * 32 + 8 * g) * 2);
            bf16x8 af1 = *(const bf16x8*)(Al + (qp * 32 + 16 + l15) * 144 + (ks * 32 + 8 * g) * 2);
#pragma unroll
            for (int dt = 0; dt < 2; ++dt) {
                const int dr = dp * 32 + dt * 16 + l15;
                bf16x8 vf = *(const bf16x8*)(
                    &Vl[bi][dr * 128 + ((ks * 64 + g * 16) ^ ((dr & 7) << 4))]);
                oacc[0][dt] = MFMA16(af0, vf, oacc[0][dt]);
                oacc[1][dt] = MFMA16(af1, vf, oacc[1][dt]);
            }
        }

        // own stage complete, then joint barrier: everyone staged + reads done
        asm volatile("s_waitcnt vmcnt(0)" ::: "memory");
        __builtin_amdgcn_s_barrier();

        mkc0 = mkn0;
        mkc1 = mkn1;
    }

    // epilogue: per-wave-disjoint 32q x 32d tile; 2 m-half blocks contend.
    // D layout per tile: row q = qt*16 + 4g + r, col d = dt*16 + l15.
    float* ob = out + ((size_t)b * 2048 + n0 + qp * 32) * 128 + dp * 32;
#pragma unroll
    for (int qt2 = 0; qt2 < 2; ++qt2)
#pragma unroll
        for (int dt = 0; dt < 2; ++dt)
#pragma unroll
            for (int r = 0; r < 4; ++r)
                unsafeAtomicAdd(&ob[(size_t)(qt2 * 16 + 4 * g + r) * 128 + dt * 16 + l15],
                                oacc[qt2][dt][r]);
}

// ---------------------------------------------------------------------------
extern "C" void kernel_launch(void* const* d_in, const int* in_sizes, int n_in,
                              void* d_out, int out_size, void* d_ws, size_t ws_size,
                              hipStream_t stream) {
    const float* x    = (const float*)d_in[0];
    const float* cond = (const float*)d_in[1];
    // d_in[2] = flags (unused by reference)
    const float* mask = (const float*)d_in[3];
    const float* Wq = (const float*)d_in[4];
    const float* bq = (const float*)d_in[5];
    const float* Wk = (const float*)d_in[6];
    const float* bk = (const float*)d_in[7];
    const float* Wv = (const float*)d_in[8];
    const float* bv = (const float*)d_in[9];
    float* out = (float*)d_out;

    char* ws = (char*)d_ws;
    __hip_bfloat16* Qo  = (__hip_bfloat16*)(ws);                       // 4 MB
    __hip_bfloat16* Ko  = (__hip_bfloat16*)(ws + (4  << 20));          // 4 MB
    __hip_bfloat16* Vt  = (__hip_bfloat16*)(ws + (8  << 20));          // 4 MB
    __hip_bfloat16* Wqt = (__hip_bfloat16*)(ws + (12 << 20));          // 32 KB
    __hip_bfloat16* Wkt = (__hip_bfloat16*)(ws + (12 << 20) + 32768);
    __hip_bfloat16* Wvt = (__hip_bfloat16*)(ws + (12 << 20) + 65536);
    float*          bias = (float*)(ws + (12 << 20) + 98304);          // 1.5 KB

    // out accumulates atomic partials from 2 m-half blocks -> zero it first
    hipMemsetAsync(d_out, 0, (size_t)out_size * sizeof(float), stream);

    prep_weights<<<64, 256, 0, stream>>>(Wq, bq, Wk, bk, Wv, bv, Wqt, Wkt, Wvt, bias);
    proj_qkv<<<256, 256, 0, stream>>>(x, cond, Wqt, Wkt, Wvt, bias, Qo, Ko, Vt);
    attn_main<<<512, 512, 0, stream>>>(Qo, Ko, Vt, mask, out);
}